// Round 6
// baseline (114.895 us; speedup 1.0000x reference)
//
#include <hip/hip_runtime.h>
#include <hip/hip_bf16.h>

#define DD 32
#define HH 32
#define WW 32
#define NN 32768
#define BB 2
#define CF 256
#define CC 21
#define FD 64
#define KK 19

typedef __attribute__((ext_vector_type(8))) short bf16x8;
typedef __attribute__((ext_vector_type(4))) float f32x4;

// 19 stencil offsets with |dx|+|dy|+|dz| <= 2 (order irrelevant: softmax+sum over k)
__device__ const int OFF[19][3] = {
    {-1,-1, 0}, {-1, 0,-1}, {-1, 0, 0}, {-1, 0, 1}, {-1, 1, 0},
    { 0,-1,-1}, { 0,-1, 0}, { 0,-1, 1}, { 0, 0,-1}, { 0, 0, 0},
    { 0, 0, 1}, { 0, 1,-1}, { 0, 1, 0}, { 0, 1, 1},
    { 1,-1, 0}, { 1, 0,-1}, { 1, 0, 0}, { 1, 0, 1}, { 1, 1, 0}
};

__device__ __forceinline__ unsigned short f2bf(float x) {
    unsigned u = __float_as_uint(x);
    u += 0x7FFFu + ((u >> 16) & 1u);       // round-to-nearest-even
    return (unsigned short)(u >> 16);
}
__device__ __forceinline__ float bf2f(unsigned short h) {
    return __uint_as_float((unsigned)h << 16);
}
#define QF(x) (((x) & 3) ^ (((x) >> 2) & 3))   // bank-spread slot xor

// ---------------- Kernel 0: weight prepack (f32 -> bf16 hi/lo fragments) ----
__global__ __launch_bounds__(256) void wprep_kernel(
    const float* __restrict__ thw, const float* __restrict__ phw,
    uint4* __restrict__ whi, uint4* __restrict__ wlo)
{
    int gid = blockIdx.x * 256 + threadIdx.x;   // 4096 fragments
    int col = gid & 127;
    int kb = (gid >> 7) & 3;
    int ks = gid >> 9;                          // 0..7
    const float* src = (col < 64) ? (thw + col) : (phw + (col - 64));
    int kbase = ks * 32 + kb * 8;
    unsigned hi4[4], lo4[4];
#pragma unroll
    for (int e2 = 0; e2 < 4; ++e2) {
        float va = src[(kbase + 2 * e2) * 64];
        float vb = src[(kbase + 2 * e2 + 1) * 64];
        unsigned short ha = f2bf(va), hb = f2bf(vb);
        unsigned short la = f2bf(va - bf2f(ha)), lb = f2bf(vb - bf2f(hb));
        hi4[e2] = (unsigned)ha | ((unsigned)hb << 16);
        lo4[e2] = (unsigned)la | ((unsigned)lb << 16);
    }
    int idx = (ks * 4 + kb) * 128 + col;
    whi[idx] = make_uint4(hi4[0], hi4[1], hi4[2], hi4[3]);
    wlo[idx] = make_uint4(lo4[0], lo4[1], lo4[2], lo4[3]);
}

// ---------------- Kernel 1: projection GEMM via split-bf16 MFMA ----------------
// 64(n) x 128(j) tile, BK=32, 4 waves each 32x64, 1024 blocks -> 4 blocks/CU.
// acc += Ahi*Bhi + Alo*Bhi + Ahi*Blo  (~f32 accuracy at bf16 MFMA rate).
__global__ __launch_bounds__(256) void proj_kernel(
    const float* __restrict__ f,
    const uint4* __restrict__ whi, const uint4* __restrict__ wlo,
    const float* __restrict__ thb, const float* __restrict__ phb,
    float* __restrict__ theta, float* __restrict__ phi)
{
    __shared__ __align__(16) unsigned short Ahi[64][4][8];    // 4 KB each
    __shared__ __align__(16) unsigned short Alo[64][4][8];
    __shared__ __align__(16) unsigned short Bhi[128][4][8];   // 8 KB each
    __shared__ __align__(16) unsigned short Blo[128][4][8];

    int tid = threadIdx.x;
    int b = blockIdx.x >> 9;                  // 512 tiles per batch
    int n0 = (blockIdx.x & 511) * 64;
    int wv = tid >> 6, lane = tid & 63;
    int wr = (wv & 1) * 32, wc = (wv >> 1) * 64;
    int fr = lane & 15, kb_r = lane >> 4;

    int arow = tid & 63;                      // A staging row
    int akb = tid >> 6;                       // A staging kb (0..3)
    int bcol = tid & 127;                     // B staging col
    int bkb0 = (tid >> 7) * 2;                // B staging kb base: 0 or 2

    const float* fb = f + (size_t)b * CF * NN + n0;

    f32x4 acc[2][4];
#pragma unroll
    for (int mi = 0; mi < 2; ++mi)
#pragma unroll
        for (int ni = 0; ni < 4; ++ni) acc[mi][ni] = (f32x4){0.f, 0.f, 0.f, 0.f};

#pragma unroll 1
    for (int k0 = 0; k0 < CF; k0 += 32) {
        // ---- stage A: 64 rows x 32 k, 8 scalar (coalesced-per-wave) loads/thread
        {
            const float* src = fb + (size_t)(k0 + akb * 8) * NN + arow;
            unsigned hi4[4], lo4[4];
#pragma unroll
            for (int e2 = 0; e2 < 4; ++e2) {
                float va = src[(size_t)(2 * e2) * NN];
                float vb = src[(size_t)(2 * e2 + 1) * NN];
                unsigned short ha = f2bf(va), hb = f2bf(vb);
                unsigned short la = f2bf(va - bf2f(ha)), lb = f2bf(vb - bf2f(hb));
                hi4[e2] = (unsigned)ha | ((unsigned)hb << 16);
                lo4[e2] = (unsigned)la | ((unsigned)lb << 16);
            }
            int slot = akb ^ QF(arow);
            *(uint4*)&Ahi[arow][slot][0] = make_uint4(hi4[0], hi4[1], hi4[2], hi4[3]);
            *(uint4*)&Alo[arow][slot][0] = make_uint4(lo4[0], lo4[1], lo4[2], lo4[3]);
        }
        // ---- stage B: prepacked fragments, straight 16B copies
        {
            const uint4* wh = whi + (size_t)(k0 >> 5) * 4 * 128;
            const uint4* wl = wlo + (size_t)(k0 >> 5) * 4 * 128;
#pragma unroll
            for (int i = 0; i < 2; ++i) {
                int kb = bkb0 + i;
                uint4 hh = wh[kb * 128 + bcol];
                uint4 ll = wl[kb * 128 + bcol];
                int slot = kb ^ QF(bcol);
                *(uint4*)&Bhi[bcol][slot][0] = hh;
                *(uint4*)&Blo[bcol][slot][0] = ll;
            }
        }
        __syncthreads();
        bf16x8 ah[2], al[2], bh[4], bl[4];
#pragma unroll
        for (int mi = 0; mi < 2; ++mi) {
            int r = wr + mi * 16 + fr;
            int slot = kb_r ^ QF(r);
            ah[mi] = *(const bf16x8*)&Ahi[r][slot][0];
            al[mi] = *(const bf16x8*)&Alo[r][slot][0];
        }
#pragma unroll
        for (int ni = 0; ni < 4; ++ni) {
            int c = wc + ni * 16 + fr;
            int slot = kb_r ^ QF(c);
            bh[ni] = *(const bf16x8*)&Bhi[c][slot][0];
            bl[ni] = *(const bf16x8*)&Blo[c][slot][0];
        }
#pragma unroll
        for (int mi = 0; mi < 2; ++mi)
#pragma unroll
            for (int ni = 0; ni < 4; ++ni) {
                acc[mi][ni] = __builtin_amdgcn_mfma_f32_16x16x32_bf16(ah[mi], bh[ni], acc[mi][ni], 0, 0, 0);
                acc[mi][ni] = __builtin_amdgcn_mfma_f32_16x16x32_bf16(al[mi], bh[ni], acc[mi][ni], 0, 0, 0);
                acc[mi][ni] = __builtin_amdgcn_mfma_f32_16x16x32_bf16(ah[mi], bl[ni], acc[mi][ni], 0, 0, 0);
            }
        __syncthreads();
    }

    // ---- epilogue: C/D col=lane&15, row=(lane>>4)*4+r
#pragma unroll
    for (int ni = 0; ni < 4; ++ni) {
        int j = wc + ni * 16 + fr;
        float bj = (j < 64) ? thb[j] : phb[j - 64];
        float* outp = (j < 64) ? (theta + (size_t)b * NN * 64 + j)
                               : (phi + (size_t)b * NN * 64 + (j - 64));
#pragma unroll
        for (int mi = 0; mi < 2; ++mi) {
            int nbase = n0 + wr + mi * 16 + kb_r * 4;
#pragma unroll
            for (int r = 0; r < 4; ++r)
                outp[(size_t)(nbase + r) * 64] = acc[mi][ni][r] + bj;
        }
    }
}

// ---------------- Kernel 2: geo projection ----------------
__global__ __launch_bounds__(256) void geo_kernel(
    const float* __restrict__ gtw, const float* __restrict__ gtb,
    const float* __restrict__ gpw, const float* __restrict__ gpb,
    float* __restrict__ gth, float* __restrict__ gph)
{
    __shared__ float pe_s[4][48];
    int tid = threadIdx.x;
    int n_base = blockIdx.x * 4;
    if (tid < 192) {
        int node = tid / 48, p = tid % 48;
        int n = n_base + node;
        int d = n >> 10, h = (n >> 5) & 31, w = n & 31;
        int a = p / 16, rem = p % 16, i = rem >> 1, sc = rem & 1;
        float coord = (a == 0) ? (float)d : (a == 1) ? (float)h : (float)w;
        float div = expf(-9.210340371976184f * (float)i * 0.125f);  // (1e-4)^(i/8)
        float ang = coord * div;
        pe_s[node][p] = sc ? cosf(ang) : sinf(ang);
    }
    __syncthreads();
    int node = tid >> 6, j = tid & 63;
    int n = n_base + node;
    float at = gtb[j], ap = gpb[j];
#pragma unroll
    for (int p = 0; p < 48; ++p) {
        float pv = pe_s[node][p];
        at += pv * gtw[p * 64 + j];
        ap += pv * gpw[p * 64 + j];
    }
    gth[(size_t)n * 64 + j] = at;
    gph[(size_t)n * 64 + j] = ap;
}

// ---------------- Kernel 2b: geo scores (batch-independent) ----------------
__global__ __launch_bounds__(256) void geo_score_kernel(
    const float* __restrict__ gth, const float* __restrict__ gph,
    float* __restrict__ gsc)
{
    int tid = threadIdx.x;
    int lane = tid & 63;
    int wv = tid >> 6;
    int sub = lane >> 4;
    int col4 = lane & 15;
    int n = blockIdx.x * 16 + wv * 4 + sub;
    int d = n >> 10, h = (n >> 5) & 31, w = n & 31;

    float4 tq = *(const float4*)(gth + (size_t)n * 64 + col4 * 4);
    const float rs = 0.2294157338705618f;  // 1/sqrt(19)

    float s[KK];
#pragma unroll
    for (int k = 0; k < KK; ++k) {
        int nd = d + OFF[k][0], nh = h + OFF[k][1], nw = w + OFF[k][2];
        bool valid = ((unsigned)nd < 32u) && ((unsigned)nh < 32u) && ((unsigned)nw < 32u);
        nd = min(max(nd, 0), 31); nh = min(max(nh, 0), 31); nw = min(max(nw, 0), 31);
        int nn = (nd << 10) + (nh << 5) + nw;
        float4 p = *(const float4*)(gph + (size_t)nn * 64 + col4 * 4);
        float part = tq.x * p.x + tq.y * p.y + tq.z * p.z + tq.w * p.w;
        part += __shfl_xor(part, 1, 16);
        part += __shfl_xor(part, 2, 16);
        part += __shfl_xor(part, 4, 16);
        part += __shfl_xor(part, 8, 16);
        s[k] = valid ? part * rs : -INFINITY;
    }
#pragma unroll
    for (int kk2 = 0; kk2 < 2; ++kk2) {
        int k = kk2 * 16 + col4;
        if (k < KK) gsc[(size_t)n * KK + k] = s[k];
    }
}

// ---------------- Kernel 3: scores + masked softmax ----------------
// writes wgt in node-major [b][n][20] (pad 20) for contiguous prop reads.
__global__ __launch_bounds__(256) void score_kernel(
    const float* __restrict__ theta, const float* __restrict__ phi,
    const float* __restrict__ gsc, float* __restrict__ wgt)
{
    int tid = threadIdx.x;
    int lane = tid & 63;
    int wv = tid >> 6;
    int sub = lane >> 4;
    int col4 = lane & 15;
    int gn = blockIdx.x * 16 + wv * 4 + sub;    // over B*N
    int b = gn >> 15;
    int n = gn & (NN - 1);
    int d = n >> 10, h = (n >> 5) & 31, w = n & 31;

    float4 tq = *(const float4*)(theta + (size_t)gn * 64 + col4 * 4);
    const float* pb = phi + (size_t)b * NN * 64;
    const float* gr = gsc + (size_t)n * KK;
    const float rs = 0.2294157338705618f;  // 1/sqrt(19)

    float s[KK];
#pragma unroll
    for (int k = 0; k < KK; ++k) {
        int nd = d + OFF[k][0], nh = h + OFF[k][1], nw = w + OFF[k][2];
        nd = min(max(nd, 0), 31); nh = min(max(nh, 0), 31); nw = min(max(nw, 0), 31);
        int nn = (nd << 10) + (nh << 5) + nw;
        float4 p = *(const float4*)(pb + (size_t)nn * 64 + col4 * 4);
        float part = tq.x * p.x + tq.y * p.y + tq.z * p.z + tq.w * p.w;
        part += __shfl_xor(part, 1, 16);
        part += __shfl_xor(part, 2, 16);
        part += __shfl_xor(part, 4, 16);
        part += __shfl_xor(part, 8, 16);
        s[k] = fmaf(part, rs, gr[k]);       // gsc carries mask (-inf) + scale
    }
    float m = s[0];
#pragma unroll
    for (int k = 1; k < KK; ++k) m = fmaxf(m, s[k]);
    float sum = 0.f;
#pragma unroll
    for (int k = 0; k < KK; ++k) { s[k] = __expf(s[k] - m); sum += s[k]; }
    float inv = 1.f / sum;
#pragma unroll
    for (int kk2 = 0; kk2 < 2; ++kk2) {
        int k = kk2 * 16 + col4;
        if (k < KK) wgt[((size_t)gn) * 20 + k] = s[k] * inv;
    }
}

// ---------------- Kernel 4: fused double propagation ----------------
// tile 4x8x8 outputs; cam halo 8x12x12 and intermediate 6x10x10 in LDS.
// w==0 for OOB edges annihilates clamped-index garbage.
__global__ __launch_bounds__(256) void prop2_kernel(
    const float* __restrict__ cam, const float* __restrict__ wgt,
    float* __restrict__ cout)
{
    __shared__ float camt[8 * 12 * 12];   // 1152
    __shared__ float inter[6 * 10 * 10];  // 600
    int blk = blockIdx.x;
    int tile = blk & 127;
    int bc = blk >> 7;                    // b*CC + c
    int b = bc / CC, c = bc % CC;
    int tw = tile & 3, th = (tile >> 2) & 3, td = tile >> 4;
    int d0 = td * 4, h0 = th * 8, w0 = tw * 8;
    const float* cb = cam + ((size_t)bc) * NN;
    const float* wb = wgt + (size_t)b * NN * 20;
    int tid = threadIdx.x;

    // stage 0: cam halo load (clamped)
    for (int i = tid; i < 1152; i += 256) {
        int lw = i % 12, lh = (i / 12) % 12, ld = i / 144;
        int gd = min(max(d0 - 2 + ld, 0), 31);
        int gh = min(max(h0 - 2 + lh, 0), 31);
        int gw = min(max(w0 - 2 + lw, 0), 31);
        camt[i] = cb[(gd << 10) + (gh << 5) + gw];
    }
    __syncthreads();

    // stage 1: intermediate on 6x10x10 (global offset -1, clamped for w fetch)
    for (int i = tid; i < 600; i += 256) {
        int lw = i % 10, lh = (i / 10) % 10, ld = i / 100;
        int gd = min(max(d0 - 1 + ld, 0), 31);
        int gh = min(max(h0 - 1 + lh, 0), 31);
        int gw = min(max(w0 - 1 + lw, 0), 31);
        const float* wr = wb + (size_t)((gd << 10) + (gh << 5) + gw) * 20;
        int cbase = (ld + 1) * 144 + (lh + 1) * 12 + (lw + 1);
        float acc = 0.f;
#pragma unroll
        for (int k = 0; k < KK; ++k)
            acc = fmaf(wr[k], camt[cbase + OFF[k][0] * 144 + OFF[k][1] * 12 + OFF[k][2]], acc);
        inter[i] = acc;
    }
    __syncthreads();

    // stage 2: final 256 outputs (in-grid by construction)
    {
        int lw = tid & 7, lh = (tid >> 3) & 7, ld = tid >> 6;
        int n = ((d0 + ld) << 10) + ((h0 + lh) << 5) + (w0 + lw);
        const float* wr = wb + (size_t)n * 20;
        int ibase = (ld + 1) * 100 + (lh + 1) * 10 + (lw + 1);
        float acc = 0.f;
#pragma unroll
        for (int k = 0; k < KK; ++k)
            acc = fmaf(wr[k], inter[ibase + OFF[k][0] * 100 + OFF[k][1] * 10 + OFF[k][2]], acc);
        cout[(size_t)bc * NN + n] = acc;
    }
}

extern "C" void kernel_launch(void* const* d_in, const int* in_sizes, int n_in,
                              void* d_out, int out_size, void* d_ws, size_t ws_size,
                              hipStream_t stream) {
    const float* cam = (const float*)d_in[0];
    const float* f   = (const float*)d_in[1];
    const float* thw = (const float*)d_in[2];
    const float* thb = (const float*)d_in[3];
    const float* phw = (const float*)d_in[4];
    const float* phb = (const float*)d_in[5];
    const float* gtw = (const float*)d_in[6];
    const float* gtb = (const float*)d_in[7];
    const float* gpw = (const float*)d_in[8];
    const float* gpb = (const float*)d_in[9];

    float* ws    = (float*)d_ws;
    float* theta = ws;                                   // [B,N,64]
    float* phi   = theta + (size_t)BB * NN * 64;         // [B,N,64]
    float* gth   = phi   + (size_t)BB * NN * 64;         // [N,64]
    float* gph   = gth   + (size_t)NN * 64;              // [N,64]
    float* wgt   = gph   + (size_t)NN * 64;              // [B,N,20] node-major
    float* gsc   = wgt   + (size_t)BB * NN * 20;         // [N,19]
    uint4* whi   = (uint4*)(gsc + (size_t)NN * KK);      // 4096 uint4
    uint4* wlo   = whi + 4096;                           // 4096 uint4

    wprep_kernel<<<16, 256, 0, stream>>>(thw, phw, whi, wlo);
    proj_kernel<<<1024, 256, 0, stream>>>(f, whi, wlo, thb, phb, theta, phi);
    geo_kernel<<<NN / 4, 256, 0, stream>>>(gtw, gtb, gpw, gpb, gth, gph);
    geo_score_kernel<<<NN / 16, 256, 0, stream>>>(gth, gph, gsc);
    score_kernel<<<BB * NN / 16, 256, 0, stream>>>(theta, phi, gsc, wgt);
    prop2_kernel<<<BB * CC * 128, 256, 0, stream>>>(cam, wgt, (float*)d_out);
}

// Round 7
// 97.563 us; speedup vs baseline: 1.1776x; 1.1776x over previous
//
#include <hip/hip_runtime.h>
#include <hip/hip_bf16.h>
#include <hip/hip_fp16.h>

#define DD 32
#define HH 32
#define WW 32
#define NN 32768
#define BB 2
#define CF 256
#define CC 21
#define FD 64
#define KK 19

typedef __attribute__((ext_vector_type(8))) short bf16x8;
typedef __attribute__((ext_vector_type(4))) float f32x4;

// 19 stencil offsets with |dx|+|dy|+|dz| <= 2 (order irrelevant: softmax+sum over k)
__device__ const int OFF[19][3] = {
    {-1,-1, 0}, {-1, 0,-1}, {-1, 0, 0}, {-1, 0, 1}, {-1, 1, 0},
    { 0,-1,-1}, { 0,-1, 0}, { 0,-1, 1}, { 0, 0,-1}, { 0, 0, 0},
    { 0, 0, 1}, { 0, 1,-1}, { 0, 1, 0}, { 0, 1, 1},
    { 1,-1, 0}, { 1, 0,-1}, { 1, 0, 0}, { 1, 0, 1}, { 1, 1, 0}
};

__device__ __forceinline__ unsigned short f2bf(float x) {
    unsigned u = __float_as_uint(x);
    u += 0x7FFFu + ((u >> 16) & 1u);       // round-to-nearest-even
    return (unsigned short)(u >> 16);
}
__device__ __forceinline__ float bf2f(unsigned short h) {
    return __uint_as_float((unsigned)h << 16);
}
#define QF(x) (((x) & 3) ^ (((x) >> 2) & 3))   // bank-spread slot xor

// ---------------- Kernel A: geo projection + (tail blocks) weight prepack ----
// blocks 0..8191: gth (f32) / gph (f16) for 4 nodes each.
// blocks 8192..8207: prepack proj weights to bf16 hi/lo fragments.
__global__ __launch_bounds__(256) void geo_wprep_kernel(
    const float* __restrict__ gtw, const float* __restrict__ gtb,
    const float* __restrict__ gpw, const float* __restrict__ gpb,
    const float* __restrict__ thw, const float* __restrict__ phw,
    float* __restrict__ gth, __half* __restrict__ gph,
    uint4* __restrict__ whi, uint4* __restrict__ wlo)
{
    int tid = threadIdx.x;
    if (blockIdx.x >= NN / 4) {
        // ---- weight prepack: 4096 fragments over 16 blocks
        int gid = (blockIdx.x - NN / 4) * 256 + tid;
        int col = gid & 127;
        int kb = (gid >> 7) & 3;
        int ks = gid >> 9;                          // 0..7
        const float* src = (col < 64) ? (thw + col) : (phw + (col - 64));
        int kbase = ks * 32 + kb * 8;
        unsigned hi4[4], lo4[4];
#pragma unroll
        for (int e2 = 0; e2 < 4; ++e2) {
            float va = src[(kbase + 2 * e2) * 64];
            float vb = src[(kbase + 2 * e2 + 1) * 64];
            unsigned short ha = f2bf(va), hb = f2bf(vb);
            unsigned short la = f2bf(va - bf2f(ha)), lb = f2bf(vb - bf2f(hb));
            hi4[e2] = (unsigned)ha | ((unsigned)hb << 16);
            lo4[e2] = (unsigned)la | ((unsigned)lb << 16);
        }
        int idx = (ks * 4 + kb) * 128 + col;
        whi[idx] = make_uint4(hi4[0], hi4[1], hi4[2], hi4[3]);
        wlo[idx] = make_uint4(lo4[0], lo4[1], lo4[2], lo4[3]);
        return;
    }
    __shared__ float pe_s[4][48];
    int n_base = blockIdx.x * 4;
    if (tid < 192) {
        int node = tid / 48, p = tid % 48;
        int n = n_base + node;
        int d = n >> 10, h = (n >> 5) & 31, w = n & 31;
        int a = p / 16, rem = p % 16, i = rem >> 1, sc = rem & 1;
        float coord = (a == 0) ? (float)d : (a == 1) ? (float)h : (float)w;
        float div = expf(-9.210340371976184f * (float)i * 0.125f);  // (1e-4)^(i/8)
        float ang = coord * div;
        pe_s[node][p] = sc ? cosf(ang) : sinf(ang);
    }
    __syncthreads();
    int node = tid >> 6, j = tid & 63;
    int n = n_base + node;
    float at = gtb[j], ap = gpb[j];
#pragma unroll
    for (int p = 0; p < 48; ++p) {
        float pv = pe_s[node][p];
        at += pv * gtw[p * 64 + j];
        ap += pv * gpw[p * 64 + j];
    }
    gth[(size_t)n * 64 + j] = at;
    gph[(size_t)n * 64 + j] = __float2half(ap);
}

// ---------------- Kernel 1: projection GEMM via split-bf16 MFMA ----------------
// 128x128 tile, 4 waves, BK=32. acc += Ahi*Bhi + Alo*Bhi + Ahi*Blo.
// theta out f32; phi out f16 (gathered downstream -> halve its bytes).
__global__ __launch_bounds__(256) void proj_kernel(
    const float* __restrict__ f,
    const uint4* __restrict__ whi, const uint4* __restrict__ wlo,
    const float* __restrict__ thb, const float* __restrict__ phb,
    float* __restrict__ theta, __half* __restrict__ phi)
{
    __shared__ __align__(16) unsigned short Ahi[128][4][8];   // 8 KB each
    __shared__ __align__(16) unsigned short Alo[128][4][8];
    __shared__ __align__(16) unsigned short Bhi[128][4][8];
    __shared__ __align__(16) unsigned short Blo[128][4][8];

    int tid = threadIdx.x;
    int b = blockIdx.x >> 8;                  // 256 tiles per batch
    int n0 = (blockIdx.x & 255) * 128;
    int wv = tid >> 6, lane = tid & 63;
    int wr = (wv >> 1) * 64, wc = (wv & 1) * 64;
    int fr = lane & 15, kb_r = lane >> 4;

    int srow = tid & 127;                     // staging row (A) / col (B)
    int kb0 = (tid >> 7) * 2;                 // staging kb base: 0 or 2

    const float* fb = f + (size_t)b * CF * NN + n0;

    f32x4 acc[4][4];
#pragma unroll
    for (int mi = 0; mi < 4; ++mi)
#pragma unroll
        for (int ni = 0; ni < 4; ++ni) acc[mi][ni] = (f32x4){0.f, 0.f, 0.f, 0.f};

#pragma unroll 1
    for (int k0 = 0; k0 < CF; k0 += 32) {
#pragma unroll
        for (int i = 0; i < 2; ++i) {
            int kb = kb0 + i;
            const float* src = fb + (size_t)(k0 + kb * 8) * NN + srow;
            unsigned hi4[4], lo4[4];
#pragma unroll
            for (int e2 = 0; e2 < 4; ++e2) {
                float va = src[(size_t)(2 * e2) * NN];
                float vb = src[(size_t)(2 * e2 + 1) * NN];
                unsigned short ha = f2bf(va), hb = f2bf(vb);
                unsigned short la = f2bf(va - bf2f(ha)), lb = f2bf(vb - bf2f(hb));
                hi4[e2] = (unsigned)ha | ((unsigned)hb << 16);
                lo4[e2] = (unsigned)la | ((unsigned)lb << 16);
            }
            int slot = kb ^ QF(srow);
            *(uint4*)&Ahi[srow][slot][0] = make_uint4(hi4[0], hi4[1], hi4[2], hi4[3]);
            *(uint4*)&Alo[srow][slot][0] = make_uint4(lo4[0], lo4[1], lo4[2], lo4[3]);
        }
        {
            const uint4* wh = whi + (size_t)(k0 >> 5) * 4 * 128;
            const uint4* wl = wlo + (size_t)(k0 >> 5) * 4 * 128;
#pragma unroll
            for (int i = 0; i < 2; ++i) {
                int kb = kb0 + i;
                uint4 hh = wh[kb * 128 + srow];
                uint4 ll = wl[kb * 128 + srow];
                int slot = kb ^ QF(srow);
                *(uint4*)&Bhi[srow][slot][0] = hh;
                *(uint4*)&Blo[srow][slot][0] = ll;
            }
        }
        __syncthreads();
        bf16x8 ah[4], al[4], bh[4], bl[4];
#pragma unroll
        for (int mi = 0; mi < 4; ++mi) {
            int r = wr + mi * 16 + fr;
            int slot = kb_r ^ QF(r);
            ah[mi] = *(const bf16x8*)&Ahi[r][slot][0];
            al[mi] = *(const bf16x8*)&Alo[r][slot][0];
        }
#pragma unroll
        for (int ni = 0; ni < 4; ++ni) {
            int c = wc + ni * 16 + fr;
            int slot = kb_r ^ QF(c);
            bh[ni] = *(const bf16x8*)&Bhi[c][slot][0];
            bl[ni] = *(const bf16x8*)&Blo[c][slot][0];
        }
#pragma unroll
        for (int mi = 0; mi < 4; ++mi)
#pragma unroll
            for (int ni = 0; ni < 4; ++ni) {
                acc[mi][ni] = __builtin_amdgcn_mfma_f32_16x16x32_bf16(ah[mi], bh[ni], acc[mi][ni], 0, 0, 0);
                acc[mi][ni] = __builtin_amdgcn_mfma_f32_16x16x32_bf16(al[mi], bh[ni], acc[mi][ni], 0, 0, 0);
                acc[mi][ni] = __builtin_amdgcn_mfma_f32_16x16x32_bf16(ah[mi], bl[ni], acc[mi][ni], 0, 0, 0);
            }
        __syncthreads();
    }

    // ---- epilogue: C/D col=lane&15, row=(lane>>4)*4+r; branch wave-uniform
#pragma unroll
    for (int ni = 0; ni < 4; ++ni) {
        int j = wc + ni * 16 + fr;
        if (j < 64) {
            float bj = thb[j];
            float* outp = theta + (size_t)b * NN * 64 + j;
#pragma unroll
            for (int mi = 0; mi < 4; ++mi) {
                int nbase = n0 + wr + mi * 16 + kb_r * 4;
#pragma unroll
                for (int r = 0; r < 4; ++r)
                    outp[(size_t)(nbase + r) * 64] = acc[mi][ni][r] + bj;
            }
        } else {
            float bj = phb[j - 64];
            __half* outp = phi + (size_t)b * NN * 64 + (j - 64);
#pragma unroll
            for (int mi = 0; mi < 4; ++mi) {
                int nbase = n0 + wr + mi * 16 + kb_r * 4;
#pragma unroll
                for (int r = 0; r < 4; ++r)
                    outp[(size_t)(nbase + r) * 64] = __float2half(acc[mi][ni][r] + bj);
            }
        }
    }
}

// ---------------- Kernel 2b: geo scores (batch-independent) ----------------
// wave = 4 nodes x 16 column-lanes; coalesced row loads; shfl_xor reduce.
__global__ __launch_bounds__(256) void geo_score_kernel(
    const float* __restrict__ gth, const __half* __restrict__ gph,
    float* __restrict__ gsc)
{
    int tid = threadIdx.x;
    int lane = tid & 63;
    int wv = tid >> 6;
    int sub = lane >> 4;
    int col4 = lane & 15;
    int n = blockIdx.x * 16 + wv * 4 + sub;
    int d = n >> 10, h = (n >> 5) & 31, w = n & 31;

    float4 tq = *(const float4*)(gth + (size_t)n * 64 + col4 * 4);
    const float rs = 0.2294157338705618f;  // 1/sqrt(19)

    float s[KK];
#pragma unroll
    for (int k = 0; k < KK; ++k) {
        int nd = d + OFF[k][0], nh = h + OFF[k][1], nw = w + OFF[k][2];
        bool valid = ((unsigned)nd < 32u) && ((unsigned)nh < 32u) && ((unsigned)nw < 32u);
        nd = min(max(nd, 0), 31); nh = min(max(nh, 0), 31); nw = min(max(nw, 0), 31);
        int nn = (nd << 10) + (nh << 5) + nw;
        uint2 raw = *(const uint2*)(gph + (size_t)nn * 64 + col4 * 4);
        __half2 h01 = __builtin_bit_cast(__half2, raw.x);
        __half2 h23 = __builtin_bit_cast(__half2, raw.y);
        float2 f01 = __half22float2(h01), f23 = __half22float2(h23);
        float part = tq.x * f01.x + tq.y * f01.y + tq.z * f23.x + tq.w * f23.y;
        part += __shfl_xor(part, 1, 16);
        part += __shfl_xor(part, 2, 16);
        part += __shfl_xor(part, 4, 16);
        part += __shfl_xor(part, 8, 16);
        s[k] = valid ? part * rs : -INFINITY;
    }
#pragma unroll
    for (int kk2 = 0; kk2 < 2; ++kk2) {
        int k = kk2 * 16 + col4;
        if (k < KK) gsc[(size_t)n * KK + k] = s[k];
    }
}

// ---------------- Kernel 3: scores + masked softmax ----------------
// wave = 4 nodes x 16 column-lanes; coalesced f16 phi row loads; k-major wgt.
__global__ __launch_bounds__(256) void score_kernel(
    const float* __restrict__ theta, const __half* __restrict__ phi,
    const float* __restrict__ gsc, float* __restrict__ wgt)
{
    int tid = threadIdx.x;
    int lane = tid & 63;
    int wv = tid >> 6;
    int sub = lane >> 4;
    int col4 = lane & 15;
    int gn = blockIdx.x * 16 + wv * 4 + sub;    // over B*N
    int b = gn >> 15;
    int n = gn & (NN - 1);
    int d = n >> 10, h = (n >> 5) & 31, w = n & 31;

    float4 tq = *(const float4*)(theta + (size_t)gn * 64 + col4 * 4);
    const __half* pb = phi + (size_t)b * NN * 64;
    const float* gr = gsc + (size_t)n * KK;
    const float rs = 0.2294157338705618f;  // 1/sqrt(19)

    float s[KK];
#pragma unroll
    for (int k = 0; k < KK; ++k) {
        int nd = d + OFF[k][0], nh = h + OFF[k][1], nw = w + OFF[k][2];
        nd = min(max(nd, 0), 31); nh = min(max(nh, 0), 31); nw = min(max(nw, 0), 31);
        int nn = (nd << 10) + (nh << 5) + nw;
        uint2 raw = *(const uint2*)(pb + (size_t)nn * 64 + col4 * 4);
        __half2 h01 = __builtin_bit_cast(__half2, raw.x);
        __half2 h23 = __builtin_bit_cast(__half2, raw.y);
        float2 f01 = __half22float2(h01), f23 = __half22float2(h23);
        float part = tq.x * f01.x + tq.y * f01.y + tq.z * f23.x + tq.w * f23.y;
        part += __shfl_xor(part, 1, 16);
        part += __shfl_xor(part, 2, 16);
        part += __shfl_xor(part, 4, 16);
        part += __shfl_xor(part, 8, 16);
        s[k] = fmaf(part, rs, gr[k]);       // gsc carries mask (-inf) + scale
    }
    float m = s[0];
#pragma unroll
    for (int k = 1; k < KK; ++k) m = fmaxf(m, s[k]);
    float sum = 0.f;
#pragma unroll
    for (int k = 0; k < KK; ++k) { s[k] = __expf(s[k] - m); sum += s[k]; }
    float inv = 1.f / sum;
#pragma unroll
    for (int kk2 = 0; kk2 < 2; ++kk2) {
        int k = kk2 * 16 + col4;
        if (k < KK) wgt[((size_t)b * KK + k) * NN + n] = s[k] * inv;
    }
}

// ---------------- Kernel 4: one propagation iteration (k-major weights) ------
__global__ __launch_bounds__(256) void prop_kernel(
    const float* __restrict__ cin, const float* __restrict__ wgt,
    float* __restrict__ cout)
{
    int gid = blockIdx.x * 256 + threadIdx.x;   // B*CC*N threads
    int n = gid & (NN - 1);
    int bc = gid >> 15;
    int b = bc / CC, c = bc % CC;
    int d = n >> 10, h = (n >> 5) & 31, w = n & 31;
    float acc = 0.f;
    const float* wb = wgt + (size_t)b * KK * NN;
    const float* cb = cin + ((size_t)b * CC + c) * NN;
#pragma unroll
    for (int k = 0; k < KK; ++k) {
        int nd = d + OFF[k][0], nh = h + OFF[k][1], nw = w + OFF[k][2];
        nd = min(max(nd, 0), 31); nh = min(max(nh, 0), 31); nw = min(max(nw, 0), 31);
        int nn = (nd << 10) + (nh << 5) + nw;
        acc += wb[(size_t)k * NN + n] * cb[nn];
    }
    cout[((size_t)b * CC + c) * NN + n] = acc;
}

extern "C" void kernel_launch(void* const* d_in, const int* in_sizes, int n_in,
                              void* d_out, int out_size, void* d_ws, size_t ws_size,
                              hipStream_t stream) {
    const float* cam = (const float*)d_in[0];
    const float* f   = (const float*)d_in[1];
    const float* thw = (const float*)d_in[2];
    const float* thb = (const float*)d_in[3];
    const float* phw = (const float*)d_in[4];
    const float* phb = (const float*)d_in[5];
    const float* gtw = (const float*)d_in[6];
    const float* gtb = (const float*)d_in[7];
    const float* gpw = (const float*)d_in[8];
    const float* gpb = (const float*)d_in[9];

    float*  ws    = (float*)d_ws;
    float*  theta = ws;                                           // [B,N,64] f32
    __half* phi   = (__half*)(theta + (size_t)BB * NN * 64);      // [B,N,64] f16
    float*  gth   = (float*)((char*)phi + (size_t)BB * NN * 64 * 2); // [N,64] f32
    __half* gph   = (__half*)(gth + (size_t)NN * 64);             // [N,64] f16
    float*  wgt   = (float*)((char*)gph + (size_t)NN * 64 * 2);   // [B,19,N] f32
    float*  gsc   = wgt + (size_t)BB * KK * NN;                   // [N,19] f32
    float*  cam1  = gsc + (size_t)NN * KK;                        // [B,21,N] f32
    uint4*  whi   = (uint4*)(cam1 + (size_t)BB * CC * NN);        // 4096 uint4
    uint4*  wlo   = whi + 4096;                                   // 4096 uint4

    geo_wprep_kernel<<<NN / 4 + 16, 256, 0, stream>>>(
        gtw, gtb, gpw, gpb, thw, phw, gth, gph, whi, wlo);
    proj_kernel<<<512, 256, 0, stream>>>(f, whi, wlo, thb, phb, theta, phi);
    geo_score_kernel<<<NN / 16, 256, 0, stream>>>(gth, gph, gsc);
    score_kernel<<<BB * NN / 16, 256, 0, stream>>>(theta, phi, gsc, wgt);
    prop_kernel<<<BB * CC * NN / 256, 256, 0, stream>>>(cam, wgt, cam1);
    prop_kernel<<<BB * CC * NN / 256, 256, 0, stream>>>(cam1, wgt, (float*)d_out);
}